// Round 1
// baseline (589.531 us; speedup 1.0000x reference)
//
#include <hip/hip_runtime.h>
#include <math.h>

// Problem constants (fixed by reference)
#define LEAVES 2048
#define NN     4095      // 2*LEAVES-1 total nodes
#define MEMD   150
#define IOUD   450
#define IND    300
#define HIDD   50
#define NCLSD  5

#define LB 16            // leaves per block in leaf kernel
#define NB 8             // nodes per block in level kernel

// ---------------------------------------------------------------------------
// Leaf kernel: x = emb[tok]; iou = x@W_ioux + b_ioux + b_iouh; gates; C,H.
// 256 blocks (128 groups/tree * 2 trees), 512 threads, 16 leaves/block.
// ---------------------------------------------------------------------------
__global__ __launch_bounds__(512) void k_leaf(
    const int* __restrict__ ltok, const int* __restrict__ rtok,
    const float* __restrict__ emb, const float* __restrict__ Wx,
    const float* __restrict__ bx, const float* __restrict__ bh,
    float* __restrict__ C, float* __restrict__ H)
{
    __shared__ float xs[IND][LB];     // transposed: xs[k][m]
    __shared__ float iou[LB][IOUD];
    __shared__ int   tok[LB];

    int grp  = blockIdx.x;            // 0..255
    int tree = grp >> 7;              // 128 groups per tree
    int leaf0 = (grp & 127) * LB;
    const int* toks = tree ? rtok : ltok;

    if (threadIdx.x < LB) tok[threadIdx.x] = toks[leaf0 + threadIdx.x];
    __syncthreads();

    // load 16 embedding rows, transposed into LDS (coalesced global reads)
    for (int idx = threadIdx.x; idx < LB * IND; idx += 512) {
        int m = idx / IND, k = idx - m * IND;
        xs[k][m] = emb[(size_t)tok[m] * IND + k];
    }
    __syncthreads();

    int j = threadIdx.x;
    if (j < IOUD) {
        float bias = bx[j] + bh[j];
        float acc[LB];
        #pragma unroll
        for (int m = 0; m < LB; ++m) acc[m] = bias;
        for (int k = 0; k < IND; ++k) {
            float w = Wx[k * IOUD + j];
            #pragma unroll
            for (int m = 0; m < LB; ++m) acc[m] += xs[k][m] * w;
        }
        #pragma unroll
        for (int m = 0; m < LB; ++m) iou[m][j] = acc[m];
    }
    __syncthreads();

    float* Ct = C + (size_t)tree * NN * MEMD;
    float* Ht = H + (size_t)tree * NN * MEMD;
    for (int idx = threadIdx.x; idx < LB * MEMD; idx += 512) {
        int m = idx / MEMD, d = idx - m * MEMD;
        float iv = iou[m][d], ov = iou[m][d + 150], uv = iou[m][d + 300];
        float ig = 1.f / (1.f + expf(-iv));
        float og = 1.f / (1.f + expf(-ov));
        float ug = tanhf(uv);
        float c  = ig * ug;
        float h  = og * tanhf(c);
        int node = leaf0 + m;
        Ct[node * MEMD + d] = c;
        Ht[node * MEMD + d] = h;
    }
}

// ---------------------------------------------------------------------------
// Level kernel: one level of the balanced tree, both trees.
// Each block: up to NB nodes. 750 dot-products/node (iou 450 + fl 150 + fr 150).
// ---------------------------------------------------------------------------
__global__ __launch_bounds__(512) void k_level(
    const int* __restrict__ lidx, const int* __restrict__ ridx,
    const float* __restrict__ Wh, const float* __restrict__ bh,
    const float* __restrict__ Wf, const float* __restrict__ bf,
    float* __restrict__ C, float* __restrict__ H,
    int ebase, int ncount)
{
    int bpt  = (ncount + NB - 1) / NB;
    int tree = blockIdx.x / bpt;
    int grp  = blockIdx.x - tree * bpt;
    int n0   = grp * NB;
    int nm   = min(NB, ncount - n0);

    float* Ct = C + (size_t)tree * NN * MEMD;
    float* Ht = H + (size_t)tree * NN * MEMD;

    __shared__ int   li[NB], ri[NB];
    __shared__ float hbuf[3][MEMD][NB];   // 0=hl, 1=hr, 2=hl+hr  (transposed)
    __shared__ float outs[NB][750];

    if (threadIdx.x < nm) {
        int e = ebase + n0 + threadIdx.x;
        li[threadIdx.x] = lidx[e];
        ri[threadIdx.x] = ridx[e];
    }
    __syncthreads();

    for (int idx = threadIdx.x; idx < NB * MEMD; idx += 512) {
        int m = idx / MEMD, d = idx - m * MEMD;
        float a = 0.f, b = 0.f;
        if (m < nm) {
            a = Ht[(size_t)li[m] * MEMD + d];
            b = Ht[(size_t)ri[m] * MEMD + d];
        }
        hbuf[0][d][m] = a;
        hbuf[1][d][m] = b;
        hbuf[2][d][m] = a + b;
    }
    __syncthreads();

    for (int o = threadIdx.x; o < 750; o += 512) {
        int sel, col, ncols; const float* Wm; float bias;
        if (o < 450)      { sel = 2; col = o;       ncols = 450; Wm = Wh; bias = bh[o]; }
        else if (o < 600) { sel = 0; col = o - 450; ncols = 150; Wm = Wf; bias = bf[o - 450]; }
        else              { sel = 1; col = o - 600; ncols = 150; Wm = Wf; bias = bf[o - 600]; }
        float acc[NB];
        #pragma unroll
        for (int m = 0; m < NB; ++m) acc[m] = bias;
        for (int k = 0; k < MEMD; ++k) {
            float w = Wm[k * ncols + col];
            #pragma unroll
            for (int m = 0; m < NB; ++m) acc[m] += hbuf[sel][k][m] * w;
        }
        #pragma unroll
        for (int m = 0; m < NB; ++m) outs[m][o] = acc[m];
    }
    __syncthreads();

    for (int idx = threadIdx.x; idx < nm * MEMD; idx += 512) {
        int m = idx / MEMD, d = idx - m * MEMD;
        float iv  = outs[m][d], ov = outs[m][d + 150], uv = outs[m][d + 300];
        float flv = outs[m][d + 450], frv = outs[m][d + 600];
        float ig = 1.f / (1.f + expf(-iv));
        float og = 1.f / (1.f + expf(-ov));
        float ug = tanhf(uv);
        float fl = 1.f / (1.f + expf(-flv));
        float fr = 1.f / (1.f + expf(-frv));
        float c  = ig * ug + fl * Ct[(size_t)li[m] * MEMD + d]
                           + fr * Ct[(size_t)ri[m] * MEMD + d];
        float h  = og * tanhf(c);
        int node = LEAVES + ebase + n0 + m;
        Ct[node * MEMD + d] = c;
        Ht[node * MEMD + d] = h;
    }
}

// ---------------------------------------------------------------------------
// Scores: sL[j] = Hl[last]·Hr[j], sR[i] = Hl[i]·Hr[last]
// ---------------------------------------------------------------------------
__global__ __launch_bounds__(256) void k_scores(
    const float* __restrict__ H, float* __restrict__ s)
{
    int side = blockIdx.x >> 4;                    // 16 chunks per side
    int j = ((blockIdx.x & 15) << 8) + threadIdx.x;
    const float* Hl = H;
    const float* Hr = H + (size_t)NN * MEMD;

    __shared__ float lastv[MEMD];
    const float* lastrow = (side == 0) ? (Hl + (size_t)(NN - 1) * MEMD)
                                       : (Hr + (size_t)(NN - 1) * MEMD);
    if (threadIdx.x < MEMD) lastv[threadIdx.x] = lastrow[threadIdx.x];
    __syncthreads();
    if (j >= NN) return;

    const float* src = (side == 0) ? Hr : Hl;
    float acc = 0.f;
    for (int d = 0; d < MEMD; ++d) acc += lastv[d] * src[(size_t)j * MEMD + d];
    s[side * NN + j] = acc;
}

// ---------------------------------------------------------------------------
// Softmax over 4095 scores + weighted sum of H rows. 2 blocks (side), 512 thr.
// side 0: beta  = softmax(sL) @ Hr   -> out[0..149]
// side 1: alpha = softmax(sR) @ Hl   -> out[150..299]
// ---------------------------------------------------------------------------
__global__ __launch_bounds__(512) void k_attnsum(
    const float* __restrict__ H, const float* __restrict__ s,
    float* __restrict__ p, float* __restrict__ outv)
{
    int side = blockIdx.x;
    const float* sv = s + side * NN;
    float* pv = p + side * NN;
    const float* src = (side == 0) ? (H + (size_t)NN * MEMD) : H;

    __shared__ float red[8];

    float mx = -3.4e38f;
    for (int j = threadIdx.x; j < NN; j += 512) mx = fmaxf(mx, sv[j]);
    #pragma unroll
    for (int off = 32; off; off >>= 1) mx = fmaxf(mx, __shfl_xor(mx, off));
    if ((threadIdx.x & 63) == 0) red[threadIdx.x >> 6] = mx;
    __syncthreads();
    float gmx = red[0];
    #pragma unroll
    for (int w = 1; w < 8; ++w) gmx = fmaxf(gmx, red[w]);
    __syncthreads();

    float se = 0.f;
    for (int j = threadIdx.x; j < NN; j += 512) {
        float e = expf(sv[j] - gmx);
        pv[j] = e;
        se += e;
    }
    #pragma unroll
    for (int off = 32; off; off >>= 1) se += __shfl_xor(se, off);
    if ((threadIdx.x & 63) == 0) red[threadIdx.x >> 6] = se;
    __syncthreads();
    float gse = 0.f;
    #pragma unroll
    for (int w = 0; w < 8; ++w) gse += red[w];

    int wv = threadIdx.x >> 6, ln = threadIdx.x & 63;
    for (int d = wv; d < MEMD; d += 8) {
        float acc = 0.f;
        for (int j = ln; j < NN; j += 64) acc += pv[j] * src[(size_t)j * MEMD + d];
        #pragma unroll
        for (int off = 32; off; off >>= 1) acc += __shfl_xor(acc, off);
        if (ln == 0) outv[side * MEMD + d] = acc / gse;
    }
}

// ---------------------------------------------------------------------------
// Final readout: v_l/v_r (300->150), feats, hidden sigmoid (300->50),
// logits (50->5), log_softmax. Single block.
// ---------------------------------------------------------------------------
__global__ __launch_bounds__(256) void k_final(
    const float* __restrict__ H, const float* __restrict__ ba,
    const float* __restrict__ Wattn, const float* __restrict__ battn,
    const float* __restrict__ Wwh, const float* __restrict__ bwh,
    const float* __restrict__ Wwp, const float* __restrict__ bwp,
    float* __restrict__ outp)
{
    __shared__ float catl[300], catr[300], vl[150], vr[150];
    __shared__ float feats[300], hid[50], logits[5];
    const float* Hl = H;
    const float* Hr = H + (size_t)NN * MEMD;
    int t = threadIdx.x;

    for (int d = t; d < 150; d += 256) {
        catl[d]       = Hl[(size_t)(NN - 1) * MEMD + d];
        catl[150 + d] = ba[d];          // beta
        catr[d]       = Hr[(size_t)(NN - 1) * MEMD + d];
        catr[150 + d] = ba[150 + d];    // alpha
    }
    __syncthreads();

    for (int o = t; o < 300; o += 256) {
        int d = (o < 150) ? o : o - 150;
        const float* cat = (o < 150) ? catl : catr;
        float acc = battn[d];
        for (int k = 0; k < 300; ++k) acc += cat[k] * Wattn[k * 150 + d];
        if (o < 150) vl[d] = acc; else vr[d] = acc;
    }
    __syncthreads();

    for (int d = t; d < 150; d += 256) {
        feats[d]       = vl[d] * vr[d];
        feats[150 + d] = fabsf(vl[d] - vr[d]);
    }
    __syncthreads();

    if (t < HIDD) {
        float acc = bwh[t];
        for (int k = 0; k < 300; ++k) acc += feats[k] * Wwh[k * HIDD + t];
        hid[t] = 1.f / (1.f + expf(-acc));
    }
    __syncthreads();

    if (t < NCLSD) {
        float acc = bwp[t];
        for (int g = 0; g < HIDD; ++g) acc += hid[g] * Wwp[g * NCLSD + t];
        logits[t] = acc;
    }
    __syncthreads();

    if (t == 0) {
        float m = logits[0];
        for (int c = 1; c < NCLSD; ++c) m = fmaxf(m, logits[c]);
        float sse = 0.f;
        for (int c = 0; c < NCLSD; ++c) sse += expf(logits[c] - m);
        float lse = m + logf(sse);
        for (int c = 0; c < NCLSD; ++c) outp[c] = logits[c] - lse;
    }
}

// ---------------------------------------------------------------------------
extern "C" void kernel_launch(void* const* d_in, const int* in_sizes, int n_in,
                              void* d_out, int out_size, void* d_ws, size_t ws_size,
                              hipStream_t stream)
{
    const int*   ltok  = (const int*)d_in[0];
    const int*   rtok  = (const int*)d_in[1];
    const int*   lidx  = (const int*)d_in[2];
    const int*   ridx  = (const int*)d_in[3];
    const float* emb   = (const float*)d_in[4];
    const float* Wx    = (const float*)d_in[5];
    const float* bx    = (const float*)d_in[6];
    const float* Wh    = (const float*)d_in[7];
    const float* bh    = (const float*)d_in[8];
    // d_in[9] (W_fx), d_in[10] (b_fx) are unused by the reference
    const float* Wf    = (const float*)d_in[11];
    const float* bf    = (const float*)d_in[12];
    const float* Wattn = (const float*)d_in[13];
    const float* battn = (const float*)d_in[14];
    const float* Wwh   = (const float*)d_in[15];
    const float* bwh   = (const float*)d_in[16];
    const float* Wwp   = (const float*)d_in[17];
    const float* bwp   = (const float*)d_in[18];
    float* out = (float*)d_out;

    float* ws = (float*)d_ws;
    float* C  = ws;                              // 2*NN*MEMD floats
    float* H  = C + (size_t)2 * NN * MEMD;       // 2*NN*MEMD floats
    float* s  = H + (size_t)2 * NN * MEMD;       // 2*NN
    float* p  = s + (size_t)2 * NN;              // 2*NN
    float* ba = p + (size_t)2 * NN;              // 300

    // Leaves: both trees
    k_leaf<<<dim3(256), dim3(512), 0, stream>>>(ltok, rtok, emb, Wx, bx, bh, C, H);

    // 11 levels of the balanced tree over 2048 leaves
    static const int lsz[11] = {1024, 512, 256, 128, 64, 32, 16, 8, 4, 2, 1};
    int ebase = 0;
    for (int l = 0; l < 11; ++l) {
        int n   = lsz[l];
        int bpt = (n + NB - 1) / NB;
        k_level<<<dim3(2 * bpt), dim3(512), 0, stream>>>(
            lidx, ridx, Wh, bh, Wf, bf, C, H, ebase, n);
        ebase += n;
    }

    // Attention (only last row/col of scores is ever used downstream)
    k_scores<<<dim3(32), dim3(256), 0, stream>>>(H, s);
    k_attnsum<<<dim3(2), dim3(512), 0, stream>>>(H, s, p, ba);
    k_final<<<dim3(1), dim3(256), 0, stream>>>(H, ba, Wattn, battn,
                                               Wwh, bwh, Wwp, bwp, out);
}

// Round 2
// 269.168 us; speedup vs baseline: 2.1902x; 2.1902x over previous
//
#include <hip/hip_runtime.h>
#include <math.h>

// Problem constants (fixed by reference)
#define LEAVES 2048
#define NN     4095      // 2*LEAVES-1 total nodes
#define MEMD   150
#define IOUD   450
#define IND    300
#define HIDD   50
#define NCLSD  5

#define LB 16            // leaves per block in leaf kernel
#define NB 8             // nodes per block in level kernel
#define CH 32            // chunks per side in attention partial
#define RCH 128          // rows per chunk (32*128 >= 4095)

// ---------------------------------------------------------------------------
// Leaf kernel: x = emb[tok]; iou = x@W_ioux + b_ioux + b_iouh; gates; C,H.
// 256 blocks (128 groups/tree * 2 trees), 512 threads, 16 leaves/block.
// ---------------------------------------------------------------------------
__global__ __launch_bounds__(512) void k_leaf(
    const int* __restrict__ ltok, const int* __restrict__ rtok,
    const float* __restrict__ emb, const float* __restrict__ Wx,
    const float* __restrict__ bx, const float* __restrict__ bh,
    float* __restrict__ C, float* __restrict__ H)
{
    __shared__ float xs[IND][LB];     // transposed: xs[k][m]
    __shared__ float iou[LB][IOUD];
    __shared__ int   tok[LB];

    int grp  = blockIdx.x;            // 0..255
    int tree = grp >> 7;              // 128 groups per tree
    int leaf0 = (grp & 127) * LB;
    const int* toks = tree ? rtok : ltok;

    if (threadIdx.x < LB) tok[threadIdx.x] = toks[leaf0 + threadIdx.x];
    __syncthreads();

    // load 16 embedding rows, transposed into LDS (coalesced global reads)
    for (int idx = threadIdx.x; idx < LB * IND; idx += 512) {
        int m = idx / IND, k = idx - m * IND;
        xs[k][m] = emb[(size_t)tok[m] * IND + k];
    }
    __syncthreads();

    int j = threadIdx.x;
    if (j < IOUD) {
        float bias = bx[j] + bh[j];
        float acc[LB];
        #pragma unroll
        for (int m = 0; m < LB; ++m) acc[m] = bias;
        for (int k = 0; k < IND; ++k) {
            float w = Wx[k * IOUD + j];
            #pragma unroll
            for (int m = 0; m < LB; ++m) acc[m] += xs[k][m] * w;
        }
        #pragma unroll
        for (int m = 0; m < LB; ++m) iou[m][j] = acc[m];
    }
    __syncthreads();

    float* Ct = C + (size_t)tree * NN * MEMD;
    float* Ht = H + (size_t)tree * NN * MEMD;
    for (int idx = threadIdx.x; idx < LB * MEMD; idx += 512) {
        int m = idx / MEMD, d = idx - m * MEMD;
        float iv = iou[m][d], ov = iou[m][d + 150], uv = iou[m][d + 300];
        float ig = 1.f / (1.f + expf(-iv));
        float og = 1.f / (1.f + expf(-ov));
        float ug = tanhf(uv);
        float c  = ig * ug;
        float h  = og * tanhf(c);
        int node = leaf0 + m;
        Ct[node * MEMD + d] = c;
        Ht[node * MEMD + d] = h;
    }
}

// ---------------------------------------------------------------------------
// Level kernel: one level of the balanced tree, both trees.
// Each block: up to NB nodes. 750 dot-products/node (iou 450 + fl 150 + fr 150).
// ---------------------------------------------------------------------------
__global__ __launch_bounds__(512) void k_level(
    const int* __restrict__ lidx, const int* __restrict__ ridx,
    const float* __restrict__ Wh, const float* __restrict__ bh,
    const float* __restrict__ Wf, const float* __restrict__ bf,
    float* __restrict__ C, float* __restrict__ H,
    int ebase, int ncount)
{
    int bpt  = (ncount + NB - 1) / NB;
    int tree = blockIdx.x / bpt;
    int grp  = blockIdx.x - tree * bpt;
    int n0   = grp * NB;
    int nm   = min(NB, ncount - n0);

    float* Ct = C + (size_t)tree * NN * MEMD;
    float* Ht = H + (size_t)tree * NN * MEMD;

    __shared__ int   li[NB], ri[NB];
    __shared__ float hbuf[3][MEMD][NB];   // 0=hl, 1=hr, 2=hl+hr  (transposed)
    __shared__ float outs[NB][750];

    if (threadIdx.x < nm) {
        int e = ebase + n0 + threadIdx.x;
        li[threadIdx.x] = lidx[e];
        ri[threadIdx.x] = ridx[e];
    }
    __syncthreads();

    for (int idx = threadIdx.x; idx < NB * MEMD; idx += 512) {
        int m = idx / MEMD, d = idx - m * MEMD;
        float a = 0.f, b = 0.f;
        if (m < nm) {
            a = Ht[(size_t)li[m] * MEMD + d];
            b = Ht[(size_t)ri[m] * MEMD + d];
        }
        hbuf[0][d][m] = a;
        hbuf[1][d][m] = b;
        hbuf[2][d][m] = a + b;
    }
    __syncthreads();

    for (int o = threadIdx.x; o < 750; o += 512) {
        int sel, col, ncols; const float* Wm; float bias;
        if (o < 450)      { sel = 2; col = o;       ncols = 450; Wm = Wh; bias = bh[o]; }
        else if (o < 600) { sel = 0; col = o - 450; ncols = 150; Wm = Wf; bias = bf[o - 450]; }
        else              { sel = 1; col = o - 600; ncols = 150; Wm = Wf; bias = bf[o - 600]; }
        float acc[NB];
        #pragma unroll
        for (int m = 0; m < NB; ++m) acc[m] = bias;
        for (int k = 0; k < MEMD; ++k) {
            float w = Wm[k * ncols + col];
            #pragma unroll
            for (int m = 0; m < NB; ++m) acc[m] += hbuf[sel][k][m] * w;
        }
        #pragma unroll
        for (int m = 0; m < NB; ++m) outs[m][o] = acc[m];
    }
    __syncthreads();

    for (int idx = threadIdx.x; idx < nm * MEMD; idx += 512) {
        int m = idx / MEMD, d = idx - m * MEMD;
        float iv  = outs[m][d], ov = outs[m][d + 150], uv = outs[m][d + 300];
        float flv = outs[m][d + 450], frv = outs[m][d + 600];
        float ig = 1.f / (1.f + expf(-iv));
        float og = 1.f / (1.f + expf(-ov));
        float ug = tanhf(uv);
        float fl = 1.f / (1.f + expf(-flv));
        float fr = 1.f / (1.f + expf(-frv));
        float c  = ig * ug + fl * Ct[(size_t)li[m] * MEMD + d]
                           + fr * Ct[(size_t)ri[m] * MEMD + d];
        float h  = og * tanhf(c);
        int node = LEAVES + ebase + n0 + m;
        Ct[node * MEMD + d] = c;
        Ht[node * MEMD + d] = h;
    }
}

// ---------------------------------------------------------------------------
// Scores: sL[j] = Hl[last]·Hr[j], sR[i] = Hl[i]·Hr[last]
// Wave-per-row, lanes over d (coalesced), shuffle reduce.
// ---------------------------------------------------------------------------
__global__ __launch_bounds__(512) void k_scores(
    const float* __restrict__ H, float* __restrict__ s)
{
    int side = blockIdx.x >> 4;                    // 16 blocks per side
    int blk  = blockIdx.x & 15;
    const float* Hl = H;
    const float* Hr = H + (size_t)NN * MEMD;

    __shared__ float lastv[MEMD];
    const float* lastrow = (side == 0) ? (Hl + (size_t)(NN - 1) * MEMD)
                                       : (Hr + (size_t)(NN - 1) * MEMD);
    if (threadIdx.x < MEMD) lastv[threadIdx.x] = lastrow[threadIdx.x];
    __syncthreads();

    const float* src = (side == 0) ? Hr : Hl;
    int wave = threadIdx.x >> 6, lane = threadIdx.x & 63;

    for (int j = blk * 8 + wave; j < NN; j += 128) {
        const float* row = src + (size_t)j * MEMD;
        float acc = 0.f;
        for (int d = lane; d < MEMD; d += 64) acc += lastv[d] * row[d];
        #pragma unroll
        for (int off = 32; off; off >>= 1) acc += __shfl_xor(acc, off);
        if (lane == 0) s[side * NN + j] = acc;
    }
}

// ---------------------------------------------------------------------------
// Softmax stats per side: stats[side] = {max, sum_exp}
// ---------------------------------------------------------------------------
__global__ __launch_bounds__(512) void k_stats(
    const float* __restrict__ s, float* __restrict__ stats)
{
    int side = blockIdx.x;
    const float* sv = s + side * NN;
    __shared__ float red[8];

    float mx = -3.4e38f;
    for (int j = threadIdx.x; j < NN; j += 512) mx = fmaxf(mx, sv[j]);
    #pragma unroll
    for (int off = 32; off; off >>= 1) mx = fmaxf(mx, __shfl_xor(mx, off));
    if ((threadIdx.x & 63) == 0) red[threadIdx.x >> 6] = mx;
    __syncthreads();
    float gmx = red[0];
    #pragma unroll
    for (int w = 1; w < 8; ++w) gmx = fmaxf(gmx, red[w]);
    __syncthreads();

    float se = 0.f;
    for (int j = threadIdx.x; j < NN; j += 512) se += expf(sv[j] - gmx);
    #pragma unroll
    for (int off = 32; off; off >>= 1) se += __shfl_xor(se, off);
    if ((threadIdx.x & 63) == 0) red[threadIdx.x >> 6] = se;
    __syncthreads();
    if (threadIdx.x == 0) {
        float gse = 0.f;
        #pragma unroll
        for (int w = 0; w < 8; ++w) gse += red[w];
        stats[side * 2 + 0] = gmx;
        stats[side * 2 + 1] = gse;
    }
}

// ---------------------------------------------------------------------------
// Attention partial sums: chunk of RCH rows per block.
// part[(side*CH+chunk)*MEMD + d] = sum_j exp(s[j]-mx) * src[j][d]
// ---------------------------------------------------------------------------
__global__ __launch_bounds__(256) void k_attn_partial(
    const float* __restrict__ H, const float* __restrict__ s,
    const float* __restrict__ stats, float* __restrict__ part)
{
    int side  = blockIdx.x / CH;
    int chunk = blockIdx.x - side * CH;
    const float* sv  = s + side * NN;
    const float* src = (side == 0) ? (H + (size_t)NN * MEMD) : H;
    float gmx = stats[side * 2];

    __shared__ float pv[RCH];
    int j0 = chunk * RCH;
    int jn = min(NN - j0, RCH);

    for (int t = threadIdx.x; t < jn; t += 256) pv[t] = expf(sv[j0 + t] - gmx);
    __syncthreads();

    int d = threadIdx.x;
    if (d < MEMD) {
        float acc = 0.f;
        const float* base = src + (size_t)j0 * MEMD + d;
        for (int t = 0; t < jn; ++t) acc += pv[t] * base[(size_t)t * MEMD];
        part[(size_t)(side * CH + chunk) * MEMD + d] = acc;
    }
}

// ---------------------------------------------------------------------------
// Reduce partials -> ba[side*MEMD + d] = sum_c part / sum_exp
// ---------------------------------------------------------------------------
__global__ __launch_bounds__(512) void k_attn_reduce(
    const float* __restrict__ part, const float* __restrict__ stats,
    float* __restrict__ ba)
{
    int idx = threadIdx.x;
    if (idx < 2 * MEMD) {
        int side = idx / MEMD, d = idx - side * MEMD;
        float acc = 0.f;
        #pragma unroll 4
        for (int c = 0; c < CH; ++c) acc += part[(size_t)(side * CH + c) * MEMD + d];
        ba[idx] = acc / stats[side * 2 + 1];
    }
}

// ---------------------------------------------------------------------------
// Final readout: v_l/v_r (300->150), feats, hidden sigmoid (300->50),
// logits (50->5), log_softmax. Single block.
// ---------------------------------------------------------------------------
__global__ __launch_bounds__(256) void k_final(
    const float* __restrict__ H, const float* __restrict__ ba,
    const float* __restrict__ Wattn, const float* __restrict__ battn,
    const float* __restrict__ Wwh, const float* __restrict__ bwh,
    const float* __restrict__ Wwp, const float* __restrict__ bwp,
    float* __restrict__ outp)
{
    __shared__ float catl[300], catr[300], vl[150], vr[150];
    __shared__ float feats[300], hid[50], logits[5];
    const float* Hl = H;
    const float* Hr = H + (size_t)NN * MEMD;
    int t = threadIdx.x;

    for (int d = t; d < 150; d += 256) {
        catl[d]       = Hl[(size_t)(NN - 1) * MEMD + d];
        catl[150 + d] = ba[d];          // beta
        catr[d]       = Hr[(size_t)(NN - 1) * MEMD + d];
        catr[150 + d] = ba[150 + d];    // alpha
    }
    __syncthreads();

    for (int o = t; o < 300; o += 256) {
        int d = (o < 150) ? o : o - 150;
        const float* cat = (o < 150) ? catl : catr;
        float acc = battn[d];
        for (int k = 0; k < 300; ++k) acc += cat[k] * Wattn[k * 150 + d];
        if (o < 150) vl[d] = acc; else vr[d] = acc;
    }
    __syncthreads();

    for (int d = t; d < 150; d += 256) {
        feats[d]       = vl[d] * vr[d];
        feats[150 + d] = fabsf(vl[d] - vr[d]);
    }
    __syncthreads();

    if (t < HIDD) {
        float acc = bwh[t];
        for (int k = 0; k < 300; ++k) acc += feats[k] * Wwh[k * HIDD + t];
        hid[t] = 1.f / (1.f + expf(-acc));
    }
    __syncthreads();

    if (t < NCLSD) {
        float acc = bwp[t];
        for (int g = 0; g < HIDD; ++g) acc += hid[g] * Wwp[g * NCLSD + t];
        logits[t] = acc;
    }
    __syncthreads();

    if (t == 0) {
        float m = logits[0];
        for (int c = 1; c < NCLSD; ++c) m = fmaxf(m, logits[c]);
        float sse = 0.f;
        for (int c = 0; c < NCLSD; ++c) sse += expf(logits[c] - m);
        float lse = m + logf(sse);
        for (int c = 0; c < NCLSD; ++c) outp[c] = logits[c] - lse;
    }
}

// ---------------------------------------------------------------------------
extern "C" void kernel_launch(void* const* d_in, const int* in_sizes, int n_in,
                              void* d_out, int out_size, void* d_ws, size_t ws_size,
                              hipStream_t stream)
{
    const int*   ltok  = (const int*)d_in[0];
    const int*   rtok  = (const int*)d_in[1];
    const int*   lidx  = (const int*)d_in[2];
    const int*   ridx  = (const int*)d_in[3];
    const float* emb   = (const float*)d_in[4];
    const float* Wx    = (const float*)d_in[5];
    const float* bx    = (const float*)d_in[6];
    const float* Wh    = (const float*)d_in[7];
    const float* bh    = (const float*)d_in[8];
    // d_in[9] (W_fx), d_in[10] (b_fx) are unused by the reference
    const float* Wf    = (const float*)d_in[11];
    const float* bf    = (const float*)d_in[12];
    const float* Wattn = (const float*)d_in[13];
    const float* battn = (const float*)d_in[14];
    const float* Wwh   = (const float*)d_in[15];
    const float* bwh   = (const float*)d_in[16];
    const float* Wwp   = (const float*)d_in[17];
    const float* bwp   = (const float*)d_in[18];
    float* out = (float*)d_out;

    float* ws    = (float*)d_ws;
    float* C     = ws;                              // 2*NN*MEMD floats
    float* H     = C + (size_t)2 * NN * MEMD;       // 2*NN*MEMD floats
    float* s     = H + (size_t)2 * NN * MEMD;       // 2*NN
    float* stats = s + (size_t)2 * NN;              // 4
    float* part  = stats + 4;                       // 2*CH*MEMD
    float* ba    = part + (size_t)2 * CH * MEMD;    // 300

    // Leaves: both trees
    k_leaf<<<dim3(256), dim3(512), 0, stream>>>(ltok, rtok, emb, Wx, bx, bh, C, H);

    // 11 levels of the balanced tree over 2048 leaves
    static const int lsz[11] = {1024, 512, 256, 128, 64, 32, 16, 8, 4, 2, 1};
    int ebase = 0;
    for (int l = 0; l < 11; ++l) {
        int n   = lsz[l];
        int bpt = (n + NB - 1) / NB;
        k_level<<<dim3(2 * bpt), dim3(512), 0, stream>>>(
            lidx, ridx, Wh, bh, Wf, bf, C, H, ebase, n);
        ebase += n;
    }

    // Attention (only last row/col of scores is ever used downstream)
    k_scores<<<dim3(32), dim3(512), 0, stream>>>(H, s);
    k_stats<<<dim3(2), dim3(512), 0, stream>>>(s, stats);
    k_attn_partial<<<dim3(2 * CH), dim3(256), 0, stream>>>(H, s, stats, part);
    k_attn_reduce<<<dim3(1), dim3(512), 0, stream>>>(part, stats, ba);
    k_final<<<dim3(1), dim3(256), 0, stream>>>(H, ba, Wattn, battn,
                                               Wwh, bwh, Wwp, bwp, out);
}